// Round 19
// baseline (17.017 us; speedup 1.0000x reference)
//
#include <hip/hip_runtime.h>
#include <hip/hip_bf16.h>

// Problem dims (fixed): n=128, d=256, ic=16, oc=16, r=10
// x:   [n, d, ic, r]  f32; w: [d, ic, oc, r] f32; out: [n, d, oc, r] f32
// out[n,d,oc,r] = log( sum_ic exp(x)*exp(w) ) - log( sum_ic exp(w) )
//
// v19 = v18 (MFMA, 4 blocks/CU, all-wave mt/rh split; 16.7us) +
//  (a) dense-store epilogue: acc -> res LDS (stride-164 f32, v5-proven),
//      then 8 thr/row read back 20 contiguous floats -> 5x dwordx4 store;
//      every wave-store instr = 1KB contiguous, 100% line utilization
//      (v13..v18 stored 8-20B pieces at 40B stride -> partial lines;
//      fill kernel proves dense writes reach 6.5 TB/s).
//      res ALIASES es/ws (dead after MFMA+lcs barrier) -> LDS still 24 KB.
//  (b) v_cvt_pk_bf16_f32 for x-stage packing (1 instr per bf16 pair).

typedef __attribute__((ext_vector_type(8))) short bf16x8;
typedef __attribute__((ext_vector_type(4))) float f32x4;

#define ES_BYTES 10752            // 32 * 168 shorts
#define WS_BYTES 12800            // 10 * 640 shorts
#define SMEM_BYTES 23552          // es+ws; res (20992) aliases from offset 0

__device__ __forceinline__ unsigned short f2bf(float v) {
    unsigned u = __float_as_uint(v);
    u += 0x7FFF + ((u >> 16) & 1);
    return (unsigned short)(u >> 16);
}

__global__ __launch_bounds__(256, 4) void fused_mfma_kernel(const float* __restrict__ x,
                                                            const float* __restrict__ w,
                                                            float* __restrict__ out) {
    __shared__ __align__(16) char smem[SMEM_BYTES];
    __shared__ float lcs[160];

    unsigned short* es  = reinterpret_cast<unsigned short*>(smem);            // [n_l][r*16+ic]
    unsigned short* ws_ = reinterpret_cast<unsigned short*>(smem + ES_BYTES); // [r][oc*40+slot]
    float*          res = reinterpret_cast<float*>(smem);                     // [n_l][164] (aliased)

    const int tid = threadIdx.x;
    const int d   = blockIdx.x & 255;
    const int n_b = (blockIdx.x >> 8) << 5;      // 0,32,64,96

    // ---- phase 1: stage exp(x) (cvt_pk) + exp(w) + B-pad zeros --------------
    {
        const int n_l  = tid >> 3;               // 0..31
        const int part = tid & 7;                // ic pair (2part, 2part+1)
        const float* xg = x + ((n_b + n_l) * 256 + d) * 160 + part * 20;
        float4 xv[5];
#pragma unroll
        for (int k = 0; k < 5; ++k) xv[k] = *reinterpret_cast<const float4*>(xg + 4 * k);

        const float* wgp = w + d * 2560 + tid * 10;
        float wv[10];
#pragma unroll
        for (int k = 0; k < 5; ++k) {
            float2 v2 = *reinterpret_cast<const float2*>(wgp + 2 * k);
            wv[2 * k] = v2.x; wv[2 * k + 1] = v2.y;
        }

        const float* xf = reinterpret_cast<const float*>(xv);
        unsigned short* erow = &es[n_l * 168];
#pragma unroll
        for (int r = 0; r < 10; ++r) {
            const float e0 = __expf(xf[r]);
            const float e1 = __expf(xf[10 + r]);
            unsigned v;
            asm("v_cvt_pk_bf16_f32 %0, %1, %2" : "=v"(v) : "v"(e0), "v"(e1));
            *reinterpret_cast<unsigned*>(&erow[r * 16 + part * 2]) = v;
        }

        const int ic = tid >> 4, oc = tid & 15;
#pragma unroll
        for (int r = 0; r < 10; ++r)
            ws_[r * 640 + oc * 40 + ic] = f2bf(__expf(wv[r]));

        if (tid < 160) {                         // zero B slots 16..31
            const int r2 = tid >> 4, oc2 = tid & 15;
            uint4* p = reinterpret_cast<uint4*>(&ws_[r2 * 640 + oc2 * 40 + 16]);
            const uint4 z = make_uint4(0u, 0u, 0u, 0u);
            p[0] = z; p[1] = z;
        }
    }
    __syncthreads();

    // ---- phase 2: lcs ((r,oc) map, b128 reads) + MFMAs (all 4 waves) -------
    if (tid < 160) {
        const int r = tid >> 4, oc = tid & 15;
        const unsigned short* p = &ws_[r * 640 + oc * 40];
        const uint4 q0 = *reinterpret_cast<const uint4*>(p);
        const uint4 q1 = *reinterpret_cast<const uint4*>(p + 8);
        const unsigned qs[8] = {q0.x, q0.y, q0.z, q0.w, q1.x, q1.y, q1.z, q1.w};
        float s = 0.f;
#pragma unroll
        for (int i = 0; i < 8; ++i) {
            s += __uint_as_float(qs[i] << 16);
            s += __uint_as_float(qs[i] & 0xFFFF0000u);
        }
        lcs[oc * 10 + r] = __logf(s);
    }

    const int wid = tid >> 6;
    const int mt  = wid & 1;             // m-tile (16 n)
    const int rh  = wid >> 1;            // r-half
    const int l   = tid & 63;
    const int lm  = l & 15;              // oc / A-row
    const int kg  = l >> 4;              // k-group

    const bf16x8 zero8 = {0, 0, 0, 0, 0, 0, 0, 0};
    const f32x4  zeroc = {0.f, 0.f, 0.f, 0.f};
    f32x4 acc[5];
#pragma unroll
    for (int h = 0; h < 5; ++h) {
        const int r = rh * 5 + h;
        bf16x8 a = (kg < 2)
            ? *reinterpret_cast<const bf16x8*>(&es[(mt * 16 + lm) * 168 + r * 16 + kg * 8])
            : zero8;
        bf16x8 b = *reinterpret_cast<const bf16x8*>(&ws_[r * 640 + lm * 40 + kg * 8]);
        acc[h] = __builtin_amdgcn_mfma_f32_16x16x32_bf16(a, b, zeroc, 0, 0, 0);
    }
    __syncthreads();   // lcs visible; es/ws_ reads done -> res may alias

    // ---- phase 3: epilogue into res (C row=kg*4+j, col=lm; m89-verified) ---
    {
        float lc[5];
#pragma unroll
        for (int h = 0; h < 5; ++h) lc[h] = lcs[lm * 10 + rh * 5 + h];
#pragma unroll
        for (int h = 0; h < 5; ++h)
#pragma unroll
            for (int j = 0; j < 4; ++j)
                res[(mt * 16 + kg * 4 + j) * 164 + lm * 10 + rh * 5 + h] =
                    __logf(acc[h][j]) - lc[h];
    }
    __syncthreads();

    // ---- phase 4: dense stores: 8 thr/row, 5x dwordx4 each (640B/row) ------
    {
        const int n2 = tid >> 3;                 // 0..31
        const int sg = tid & 7;                  // 0..7 (20 floats each)
        const float* rp = res + n2 * 164 + sg * 20;
        float4 o0 = *reinterpret_cast<const float4*>(rp);
        float4 o1 = *reinterpret_cast<const float4*>(rp + 4);
        float4 o2 = *reinterpret_cast<const float4*>(rp + 8);
        float4 o3 = *reinterpret_cast<const float4*>(rp + 12);
        float4 o4 = *reinterpret_cast<const float4*>(rp + 16);
        float* og = out + ((n_b + n2) * 256 + d) * 160 + sg * 20;
        *reinterpret_cast<float4*>(og)      = o0;
        *reinterpret_cast<float4*>(og + 4)  = o1;
        *reinterpret_cast<float4*>(og + 8)  = o2;
        *reinterpret_cast<float4*>(og + 12) = o3;
        *reinterpret_cast<float4*>(og + 16) = o4;
    }
}

extern "C" void kernel_launch(void* const* d_in, const int* in_sizes, int n_in,
                              void* d_out, int out_size, void* d_ws, size_t ws_size,
                              hipStream_t stream) {
    const float* x = (const float*)d_in[0];
    const float* w = (const float*)d_in[1];
    float* out = (float*)d_out;

    // 1024 blocks: d = bid&255, n-chunk = bid>>8 (4 chunks of 32 n)
    fused_mfma_kernel<<<1024, 256, 0, stream>>>(x, w, out);
}